// Round 25
// baseline (190.060 us; speedup 1.0000x reference)
//
#include <hip/hip_runtime.h>
#include <hip/hip_bf16.h>

typedef __bf16 bf16x8 __attribute__((ext_vector_type(8)));
typedef __bf16 bf16x4 __attribute__((ext_vector_type(4)));
typedef float  f32x4  __attribute__((ext_vector_type(4)));
typedef float  f32x16 __attribute__((ext_vector_type(16)));
typedef unsigned int uint4v __attribute__((ext_vector_type(4)));

#define NB     2
#define TT     2048
#define CC     2048
#define NH     16
#define NKV    4
#define HD     128
#define WIN    1024
#define SINKN  4
// Q pre-scale folds 1/sqrt(128) AND log2(e): softmax runs in exp2 domain.
#define QSCALE2 (0.08838834764831845f * 1.44269504088896340f)

// ---- async global->LDS, 16B per lane; LDS dest is wave-uniform base (HW adds lane*16)
__device__ __forceinline__ void lds_load16(const void* g, void* l) {
    __builtin_amdgcn_global_load_lds(
        (__attribute__((address_space(1))) void*)const_cast<void*>(g),
        (__attribute__((address_space(3))) void*)l, 16, 0, 0);
}

__device__ __forceinline__ unsigned pack2bf(float a, float b) {
    __bf16 x = (__bf16)a, y = (__bf16)b;
    unsigned short ux = __builtin_bit_cast(unsigned short, x);
    unsigned short uy = __builtin_bit_cast(unsigned short, y);
    return (unsigned)ux | ((unsigned)uy << 16);
}

__device__ __forceinline__ float fast_exp2(float x) {   // v_exp_f32 = 2^x
    float r;
    asm("v_exp_f32 %0, %1" : "=v"(r) : "v"(x));
    return r;
}

// ===================== fused prologue: cvt x, cvt W, rope tables ============
__global__ void prolog_kernel(const float* __restrict__ x,
                              const float* __restrict__ wq, const float* __restrict__ wk,
                              const float* __restrict__ wv, const float* __restrict__ wo,
                              __bf16* __restrict__ xb, __bf16* __restrict__ Wall,
                              float* __restrict__ cosT, float* __restrict__ sinT) {
    const int g = blockIdx.x * 256 + threadIdx.x;
    if (g < 2097152) {                       // x -> bf16
        const int idx = g * 4;
        const float4 v = *(const float4*)(x + idx);
        bf16x4 o;
        o[0] = (__bf16)v.x; o[1] = (__bf16)v.y; o[2] = (__bf16)v.z; o[3] = (__bf16)v.w;
        *(bf16x4*)(xb + idx) = o;
    } else if (g < 4718592) {                // weights -> bf16 (contiguous Wall|wob)
        const int idx = (g - 2097152) * 4;
        const float* src; int off;
        if (idx < 4194304)      { src = wq; off = idx; }
        else if (idx < 5242880) { src = wk; off = idx - 4194304; }
        else if (idx < 6291456) { src = wv; off = idx - 5242880; }
        else                    { src = wo; off = idx - 6291456; }
        const float4 v = *(const float4*)(src + off);
        bf16x4 o;
        o[0] = (__bf16)v.x; o[1] = (__bf16)v.y; o[2] = (__bf16)v.z; o[3] = (__bf16)v.w;
        *(bf16x4*)(Wall + idx) = o;
    } else {                                 // rope tables
        const int i = g - 4718592;           // < 131072 = 2048*64
        const int t = i >> 6, d = i & 63;
        const float inv_freq = 1.0f / powf(10000.0f, (float)d * (1.0f / 64.0f));
        const float ang = (float)t * inv_freq;
        cosT[i] = cosf(ang);
        sinT[i] = sinf(ang);
    }
}

// ============ fused post-GEMM: RoPE scatter + V transpose ===================
__global__ void scatter_vt_kernel(const __bf16* __restrict__ qkv,
                                  const float* __restrict__ cosT,
                                  const float* __restrict__ sinT,
                                  __bf16* __restrict__ Qo,   // (B*NH, T, 128), pre-scaled (exp2 domain)
                                  __bf16* __restrict__ Ko,   // (B*NKV, T, 128)
                                  __bf16* __restrict__ Vt) { // (B*NKV, 128, T)
    __shared__ __bf16 tile[64][72];
    if (blockIdx.x < 2560) {
        const int job = blockIdx.x * 256 + threadIdx.x;
        int m, d8, base_off; __bf16* outp; float scale;
        if (job < 524288) {                 // Q
            m = job >> 7;
            const int pj = job & 127;
            const int hh = pj >> 3; d8 = pj & 7;
            base_off = hh * 128;
            const int b = m >> 11, t = m & 2047;
            outp = Qo + ((size_t)(b * NH + hh) * TT + t) * HD + d8 * 8;
            scale = QSCALE2;
        } else {                            // K
            const int j2 = job - 524288;
            m = j2 >> 5;
            const int pj = j2 & 31;
            const int g = pj >> 3; d8 = pj & 7;
            base_off = 2048 + g * 128;
            const int b = m >> 11, t = m & 2047;
            outp = Ko + ((size_t)(b * NKV + g) * TT + t) * HD + d8 * 8;
            scale = 1.0f;
        }
        const int t = m & 2047;
        const __bf16* row = qkv + (size_t)m * 3072 + base_off + d8 * 8;
        const bf16x8 x1 = *(const bf16x8*)row;
        const bf16x8 x2 = *(const bf16x8*)(row + 64);
        const float4 c0 = *(const float4*)(cosT + t * 64 + d8 * 8);
        const float4 c1 = *(const float4*)(cosT + t * 64 + d8 * 8 + 4);
        const float4 s0 = *(const float4*)(sinT + t * 64 + d8 * 8);
        const float4 s1 = *(const float4*)(sinT + t * 64 + d8 * 8 + 4);
        const float cs[8] = {c0.x, c0.y, c0.z, c0.w, c1.x, c1.y, c1.z, c1.w};
        const float sn[8] = {s0.x, s0.y, s0.z, s0.w, s1.x, s1.y, s1.z, s1.w};
        bf16x8 o1, o2;
#pragma unroll
        for (int e = 0; e < 8; ++e) {
            const float a = (float)x1[e], bb = (float)x2[e];
            o1[e] = (__bf16)((a * cs[e] - bb * sn[e]) * scale);
            o2[e] = (__bf16)((bb * cs[e] + a * sn[e]) * scale);
        }
        *(bf16x8*)outp = o1;
        *(bf16x8*)(outp + 64) = o2;
    } else {
        const int idx2 = blockIdx.x - 2560;       // old (32,2,8) grid flattened
        const int t0 = (idx2 & 31) << 6, d0 = ((idx2 >> 5) & 1) << 6, bkv = idx2 >> 6;
        const int b = bkv >> 2, g = bkv & 3;
        const int r = threadIdx.x >> 2, cg = threadIdx.x & 3;
        const __bf16* src = qkv + (size_t)(b * TT + t0 + r) * 3072 + 2560 + g * 128 + d0 + cg * 16;
        *(bf16x8*)&tile[r][cg * 16]     = *(const bf16x8*)src;
        *(bf16x8*)&tile[r][cg * 16 + 8] = *(const bf16x8*)(src + 8);
        __syncthreads();
        __bf16* dst = Vt + ((size_t)bkv * HD + d0 + r) * TT + t0 + cg * 16;
        bf16x8 o0, o1;
#pragma unroll
        for (int c2 = 0; c2 < 8; ++c2) {
            o0[c2] = tile[cg * 16 + c2][r];
            o1[c2] = tile[cg * 16 + 8 + c2][r];
        }
        *(bf16x8*)dst = o0;
        *(bf16x8*)(dst + 8) = o1;
    }
}

// ==== GEMM-8W-T4: BM=256 BN=128 BK=64, 3-buffer 2-deep prefetch, counted ====
// vmcnt(6) at tile boundary leaves next-next tile's 6 loads in flight across
// a RAW s_barrier (T4: never drain to 0 in the main loop). Grid 384 (%8==0).
// 8 waves as 2(M)x4(N); wave owns 128x32 of C. LDS 3x(32+16) = 144KB.
template <int OUT_BF16>
__global__ __launch_bounds__(512, 2) void gemm_bt8(const __bf16* __restrict__ A,
                                                   const __bf16* __restrict__ Bm,
                                                   void* __restrict__ C,
                                                   int M, int N, int K) {
    __shared__ __align__(16) __bf16 lA[3][256 * 64];   // 3 x 32KB
    __shared__ __align__(16) __bf16 lB[3][128 * 64];   // 3 x 16KB
    const int tid = threadIdx.x;
    const int lane = tid & 63;
    const int w = tid >> 6;
    const int wm = w >> 2, wn = w & 3;                 // wave tile: rows wm*128, cols wn*32
    const int nbn = N >> 7;
    const int nwg = (M >> 8) * nbn;
    const int chunk = nwg >> 3;                        // nwg % 8 == 0 (384)
    const int swz = (blockIdx.x & 7) * chunk + (blockIdx.x >> 3);
    const int bm = swz / nbn, bn = swz % nbn;
    const int m0 = bm << 8, n0 = bn << 7;
    const int lr = lane & 15, lh = lane >> 4;
    const int NT = K >> 6;

    auto stageT = [&](int kt, int buf) {               // 6 loads/thread per tile
#pragma unroll
        for (int i = 0; i < 4; ++i) {                  // A: 256x64 = 32KB
            const int d = i * 8192 + tid * 16;
            const int row = d >> 7;
            const int colb = (d & 127) ^ ((row & 7) << 4);
            lds_load16(A + (size_t)(m0 + row) * K + kt * 64 + (colb >> 1),
                       (char*)lA[buf] + i * 8192 + w * 1024);
        }
#pragma unroll
        for (int i = 0; i < 2; ++i) {                  // B: 128x64 = 16KB
            const int d = i * 8192 + tid * 16;
            const int row = d >> 7;
            const int colb = (d & 127) ^ ((row & 7) << 4);
            lds_load16(Bm + (size_t)(n0 + row) * K + kt * 64 + (colb >> 1),
                       (char*)lB[buf] + i * 8192 + w * 1024);
        }
    };

    f32x4 acc[8][2] = {};

    // prologue: 2-deep prefetch (tiles 0 and 1), wait tile 0 only (vmcnt 6)
    stageT(0, 0);
    stageT(1, 1);
    asm volatile("s_waitcnt vmcnt(6)" ::: "memory");
    __builtin_amdgcn_s_barrier();
    __builtin_amdgcn_sched_barrier(0);

    for (int kt = 0; kt < NT; ++kt) {
        const int cur = kt % 3;
        const char* bA = (const char*)lA[cur];
        const char* bB = (const char*)lB[cur];

        bf16x8 aF[4][2], bf2[2][2];
        // ---- phase 0: A row-half 0 (mf 0-3) x B (nf 0-1) ----
#pragma unroll
        for (int mf = 0; mf < 4; ++mf)
#pragma unroll
            for (int ks = 0; ks < 2; ++ks) {
                const int row = wm * 128 + mf * 16 + lr;
                const int cb = (ks * 64 + lh * 16) ^ ((row & 7) << 4);
                aF[mf][ks] = *(const bf16x8*)(bA + row * 128 + cb);
            }
#pragma unroll
        for (int nf = 0; nf < 2; ++nf)
#pragma unroll
            for (int ks = 0; ks < 2; ++ks) {
                const int row = wn * 32 + nf * 16 + lr;
                const int cb = (ks * 64 + lh * 16) ^ ((row & 7) << 4);
                bf2[nf][ks] = *(const bf16x8*)(bB + row * 128 + cb);
            }
        if (kt + 2 < NT) stageT(kt + 2, (kt + 2) % 3);  // 2-deep prefetch
        __builtin_amdgcn_s_setprio(1);
#pragma unroll
        for (int mf = 0; mf < 4; ++mf)
#pragma unroll
            for (int nf = 0; nf < 2; ++nf)
#pragma unroll
                for (int ks = 0; ks < 2; ++ks)
                    acc[mf][nf] = __builtin_amdgcn_mfma_f32_16x16x32_bf16(aF[mf][ks], bf2[nf][ks], acc[mf][nf], 0, 0, 0);
        __builtin_amdgcn_s_setprio(0);

        // ---- phase 1: A row-half 1 (mf 4-7) x B ----
#pragma unroll
        for (int mf = 0; mf < 4; ++mf)
#pragma unroll
            for (int ks = 0; ks < 2; ++ks) {
                const int row = wm * 128 + 64 + mf * 16 + lr;
                const int cb = (ks * 64 + lh * 16) ^ ((row & 7) << 4);
                aF[mf][ks] = *(const bf16x8*)(bA + row * 128 + cb);
            }
        __builtin_amdgcn_s_setprio(1);
#pragma unroll
        for (int mf = 0; mf < 4; ++mf)
#pragma unroll
            for (int nf = 0; nf < 2; ++nf)
#pragma unroll
                for (int ks = 0; ks < 2; ++ks)
                    acc[mf + 4][nf] = __builtin_amdgcn_mfma_f32_16x16x32_bf16(aF[mf][ks], bf2[nf][ks], acc[mf + 4][nf], 0, 0, 0);
        __builtin_amdgcn_s_setprio(0);

        // ---- tile boundary: wait NEXT tile's loads only (counted, T4) ----
        if (kt + 2 < NT) asm volatile("s_waitcnt vmcnt(6)" ::: "memory");
        else             asm volatile("s_waitcnt vmcnt(0)" ::: "memory");
        __builtin_amdgcn_s_barrier();            // raw: no vmcnt re-drain
        __builtin_amdgcn_sched_barrier(0);
    }

    // ---- epilogue: C layout col=lr, row=lh*4+r ----
#pragma unroll
    for (int mf = 0; mf < 8; ++mf)
#pragma unroll
        for (int nf = 0; nf < 2; ++nf)
#pragma unroll
            for (int r = 0; r < 4; ++r) {
                const size_t row = m0 + wm * 128 + mf * 16 + lh * 4 + r;
                const size_t col = n0 + wn * 32 + nf * 16 + lr;
                if (OUT_BF16) ((__bf16*)C)[row * N + col] = (__bf16)acc[mf][nf][r];
                else          ((float*)C)[row * N + col]  = acc[mf][nf][r];
            }
}

// ====== GEMM-4W (out-proj): 128x128, BK=64, XOR-swizzled, dbuf, T1 ==========
template <int OUT_BF16>
__global__ __launch_bounds__(256, 2) void gemm_bt(const __bf16* __restrict__ A,
                                                  const __bf16* __restrict__ Bm,
                                                  void* __restrict__ C,
                                                  int M, int N, int K) {
    __shared__ __align__(16) __bf16 lA[2][128 * 64];   // 2 x 16KB
    __shared__ __align__(16) __bf16 lB[2][128 * 64];   // 2 x 16KB
    const int tid = threadIdx.x;
    const int lane = tid & 63;
    const int w = tid >> 6;
    const int wr = w >> 1, wc = w & 1;
    const int nbn = N >> 7;
    const int nwg = (M >> 7) * nbn;
    const int chunk = nwg >> 3;                        // nwg % 8 == 0 (512)
    const int swz = (blockIdx.x & 7) * chunk + (blockIdx.x >> 3);
    const int bm = swz / nbn, bn = swz % nbn;
    const int m0 = bm << 7, n0 = bn << 7;
    const int lr = lane & 15, lh = lane >> 4;
    f32x4 acc[4][4] = {};

    auto stage = [&](int k0, int buf) {
#pragma unroll
        for (int i = 0; i < 4; ++i) {                  // 256 thr x 16B = 32 rows/chunk
            const int d = i * 4096 + tid * 16;
            const int row = d >> 7;
            const int colb = (d & 127) ^ ((row & 7) << 4);
            lds_load16(A + (size_t)(m0 + row) * K + k0 + (colb >> 1),
                       (char*)lA[buf] + i * 4096 + w * 1024);
            lds_load16(Bm + (size_t)(n0 + row) * K + k0 + (colb >> 1),
                       (char*)lB[buf] + i * 4096 + w * 1024);
        }
    };

    stage(0, 0);
    asm volatile("s_waitcnt vmcnt(0)" ::: "memory");
    __syncthreads();

    const int NT = K >> 6;
    for (int kt = 0; kt < NT; ++kt) {
        const int buf = kt & 1;
        if (kt + 1 < NT) stage((kt + 1) << 6, buf ^ 1);   // prefetch before compute

        const char* bA = (const char*)lA[buf];
        const char* bB = (const char*)lB[buf];
        bf16x8 af[4][2], bfr[4][2];
#pragma unroll
        for (int t = 0; t < 4; ++t)
#pragma unroll
            for (int ks = 0; ks < 2; ++ks) {
                const int rowa = wr * 64 + t * 16 + lr;
                const int cba = (ks * 64 + lh * 16) ^ ((rowa & 7) << 4);
                af[t][ks] = *(const bf16x8*)(bA + rowa * 128 + cba);
                const int rowb = wc * 64 + t * 16 + lr;
                const int cbb = (ks * 64 + lh * 16) ^ ((rowb & 7) << 4);
                bfr[t][ks] = *(const bf16x8*)(bB + rowb * 128 + cbb);
            }
#pragma unroll
        for (int mt = 0; mt < 4; ++mt)
#pragma unroll
            for (int nt = 0; nt < 4; ++nt)
#pragma unroll
                for (int ks = 0; ks < 2; ++ks)
                    acc[mt][nt] = __builtin_amdgcn_mfma_f32_16x16x32_bf16(af[mt][ks], bfr[nt][ks], acc[mt][nt], 0, 0, 0);

        asm volatile("s_waitcnt vmcnt(0)" ::: "memory");
        __syncthreads();
    }

    const int r0 = (lane >> 4) * 4;
#pragma unroll
    for (int mt = 0; mt < 4; ++mt)
#pragma unroll
        for (int nt = 0; nt < 4; ++nt)
#pragma unroll
            for (int r = 0; r < 4; ++r) {
                const size_t row = m0 + wr * 64 + mt * 16 + r0 + r;
                const size_t col = n0 + wc * 64 + nt * 16 + lr;
                if (OUT_BF16) ((__bf16*)C)[row * N + col] = (__bf16)acc[mt][nt][r];
                else          ((float*)C)[row * N + col]  = acc[mt][nt][r];
            }
}

// ============================== flash attention =============================
// R19-exact (best measured: 55.2 us): 32x32x16 MFMA, block = 256 thr = 4
// waves = 4 heads; each wave computes all 32 q-rows of its head. XCD-pinned.
__global__ __launch_bounds__(256, 2) void attn_kernel(const __bf16* __restrict__ Q,
                                                      const __bf16* __restrict__ Kg,
                                                      const __bf16* __restrict__ Vt,
                                                      __bf16* __restrict__ Y) {
    const int id = blockIdx.x;
    const int grp = id & 7;                     // -> XCD (dispatch round-robin)
    const int pos = id >> 3;                    // 0..63
    const int kv = grp & 3, b = grp >> 2;
    const int qt2 = 63 - pos;                   // LPT within XCD
    const int q0 = qt2 << 5;                    // 32 q-rows per block
    const int tid = threadIdx.x, lane = tid & 63, w = tid >> 6;
    const int l31 = lane & 31, hi = lane >> 5;
    const int h  = kv * 4 + w;                  // wave = head

    __shared__ __align__(16) __bf16 lK[64 * 128];   // 16KB [k][d] 256B rows
    __shared__ __align__(16) __bf16 lV[128 * 64];   // 16KB V^T [d][t] 128B rows

    // Q as B-fragments: qf[c] = Q[q0+l31][c*16 + hi*8 .. +8]
    bf16x8 qf[8];
    {
        const __bf16* Qb = Q + ((size_t)(b * NH + h) * TT + q0) * HD;
#pragma unroll
        for (int c = 0; c < 8; ++c)
            qf[c] = *(const bf16x8*)(Qb + l31 * HD + c * 16 + hi * 8);
    }

    f32x16 acc[4] = {};                         // O: col d = dt*32+l31, row q pattern
    float mrun = -1e30f, lrun = 0.f;
    const int iq = q0 + l31;                    // this lane's q (S-layout)

    const __bf16* Kb = Kg + (size_t)(b * NKV + kv) * TT * HD;
    const __bf16* Vb = Vt + (size_t)(b * NKV + kv) * HD * TT;
    const int jend = qt2 >> 1;
    const int jsw  = (q0 > WIN) ? ((q0 - WIN) >> 6) : 0;

    for (int jb = 0; jb <= jend; ++jb) {
        if (jb > 0 && jb < jsw) continue;       // fully-masked (keep sink jb=0)
        const int j0 = jb << 6;
        __syncthreads();
        // stage 32KB with 256 thr: 4 chunks K (16 rows each), 4 chunks V (32 rows)
#pragma unroll
        for (int i = 0; i < 4; ++i) {
            const int o = i * 4096 + tid * 16;
            {   // K [64][128]: 256B rows
                const int row = o >> 8;
                const int colb = (o & 255) ^ ((row & 7) << 4);
                lds_load16(Kb + (size_t)(j0 + row) * HD + (colb >> 1),
                           (char*)lK + i * 4096 + w * 1024);
            }
            {   // V^T [128][64]: 128B rows
                const int row = o >> 7;
                const int colb = (o & 127) ^ ((row & 7) << 4);
                lds_load16(Vb + (size_t)row * TT + j0 + (colb >> 1),
                           (char*)lV + i * 4096 + w * 1024);
            }
        }
        asm volatile("s_waitcnt vmcnt(0)" ::: "memory");
        __syncthreads();

        // ---- S^T = K Q^T : two 32x32 tiles (kt2), K over d in 8 slices ----
        f32x16 st[2];
#pragma unroll
        for (int kt2 = 0; kt2 < 2; ++kt2) {
            f32x16 s = {};
#pragma unroll
            for (int c = 0; c < 8; ++c) {
                const int row = kt2 * 32 + l31;
                const int cb = (c * 32 + hi * 16) ^ ((row & 7) << 4);
                const bf16x8 kf = *(const bf16x8*)((const char*)lK + row * 256 + cb);
                s = __builtin_amdgcn_mfma_f32_32x32x16_bf16(kf, qf[c], s, 0, 0, 0);
            }
            st[kt2] = s;
        }

        // ---- mask (q fixed per lane; k in reg pattern) ----
        const bool fullTile = (j0 + 63 <= q0) && (q0 + 31 - j0 <= WIN);
        if (!fullTile) {
#pragma unroll
            for (int kt2 = 0; kt2 < 2; ++kt2)
#pragma unroll
                for (int rr = 0; rr < 16; ++rr) {
                    const int j = j0 + kt2 * 32 + (rr & 3) + 8 * (rr >> 2) + 4 * hi;
                    const bool ok = (j <= iq) && ((iq - j <= WIN) || (j < SINKN));
                    if (!ok) st[kt2][rr] = -1e30f;
                }
        }

        // ---- row max: 31 in-lane + 1 shuffle (L/L+32 share q-col) ----
        float mx = st[0][0];
#pragma unroll
        for (int kt2 = 0; kt2 < 2; ++kt2)
#pragma unroll
            for (int rr = 0; rr < 16; ++rr) mx = fmaxf(mx, st[kt2][rr]);
        mx = fmaxf(mx, __shfl_xor(mx, 32, 64));

        // ---- defer-max (T13; 11.53 log2-units = 8 nats) ----
        if (!__all(mx - mrun <= 11.53f)) {
            const float mnew = fmaxf(mrun, mx);
            const float corr = fast_exp2(mrun - mnew);
            mrun = mnew;
            lrun *= corr;
#pragma unroll
            for (int rr = 0; rr < 16; ++rr) {
                const float cq = __shfl(corr, (rr & 3) + 8 * (rr >> 2) + 4 * hi, 64);
#pragma unroll
                for (int dt = 0; dt < 4; ++dt) acc[dt][rr] *= cq;
            }
        }

        // ---- P = 2^(S - m), row sum (partial per half, combined via xor32) ----
        float rsum = 0.f;
#pragma unroll
        for (int kt2 = 0; kt2 < 2; ++kt2)
#pragma unroll
            for (int rr = 0; rr < 16; ++rr) {
                const float p = fast_exp2(st[kt2][rr] - mrun);
                st[kt2][rr] = p;
                rsum += p;
            }
        rsum += __shfl_xor(rsum, 32, 64);
        lrun += rsum;

        // ---- P -> A-fragments pa[c] (k-slice c of 16): lane<->lane+32 swap ----
        bf16x8 pa[4];
#pragma unroll
        for (int c = 0; c < 4; ++c) {
            const int kt2 = c >> 1, g = c & 1, base = 8 * g;
            const unsigned u1a = pack2bf(st[kt2][base + 0], st[kt2][base + 1]);
            const unsigned u1b = pack2bf(st[kt2][base + 2], st[kt2][base + 3]);
            const unsigned u2a = pack2bf(st[kt2][base + 4], st[kt2][base + 5]);
            const unsigned u2b = pack2bf(st[kt2][base + 6], st[kt2][base + 7]);
            const unsigned p1a = (unsigned)__shfl_xor((int)u1a, 32, 64);
            const unsigned p1b = (unsigned)__shfl_xor((int)u1b, 32, 64);
            const unsigned p2a = (unsigned)__shfl_xor((int)u2a, 32, 64);
            const unsigned p2b = (unsigned)__shfl_xor((int)u2b, 32, 64);
            uint4v uv;
            uv[0] = hi ? p2a : u1a;
            uv[1] = hi ? p2b : u1b;
            uv[2] = hi ? u2a : p1a;
            uv[3] = hi ? u2b : p1b;
            pa[c] = __builtin_bit_cast(bf16x8, uv);
        }

        // ---- O += P V : 4 d-tiles x 4 k-slices ----
#pragma unroll
        for (int dt = 0; dt < 4; ++dt) {
            const int row = dt * 32 + l31;
            const int swzr = (row & 7) << 4;
#pragma unroll
            for (int c = 0; c < 4; ++c) {
                const int cb = (c * 32 + hi * 16) ^ swzr;
                const bf16x8 vf = *(const bf16x8*)((const char*)lV + row * 128 + cb);
                acc[dt] = __builtin_amdgcn_mfma_f32_32x32x16_bf16(pa[c], vf, acc[dt], 0, 0, 0);
            }
        }
    }

    // ---- epilogue: q = (rr&3)+8*(rr>>2)+4hi, d = dt*32+l31 ----
    const float inv = 1.f / lrun;
    float invq[16];
#pragma unroll
    for (int rr = 0; rr < 16; ++rr)
        invq[rr] = __shfl(inv, (rr & 3) + 8 * (rr >> 2) + 4 * hi, 64);
#pragma unroll
    for (int dt = 0; dt < 4; ++dt)
#pragma unroll
        for (int rr = 0; rr < 16; ++rr) {
            const int qrow = (rr & 3) + 8 * (rr >> 2) + 4 * hi;
            Y[((size_t)b * TT + q0 + qrow) * CC + h * HD + dt * 32 + l31] =
                (__bf16)(acc[dt][rr] * invq[rr]);
        }
}

// ================================ launch ====================================
extern "C" void kernel_launch(void* const* d_in, const int* in_sizes, int n_in,
                              void* d_out, int out_size, void* d_ws, size_t ws_size,
                              hipStream_t stream) {
    const float* x  = (const float*)d_in[0];
    const float* wq = (const float*)d_in[1];
    const float* wk = (const float*)d_in[2];
    const float* wv = (const float*)d_in[3];
    const float* wo = (const float*)d_in[4];
    float* out = (float*)d_out;

    char* ws = (char*)d_ws;
    size_t off = 0;
    auto alloc = [&](size_t bytes) { char* p = ws + off; off += bytes; return p; };
    __bf16* xb   = (__bf16*)alloc(16777216);   // x bf16 (4096x2048); reused as Y after attn
    __bf16* Wall = (__bf16*)alloc(12582912);   // [wq;wk;wv] (3072x2048)
    __bf16* wob  = (__bf16*)alloc(8388608);    // wo (2048x2048), contiguous after Wall
    __bf16* qkv  = (__bf16*)alloc(25165824);   // (4096x3072)
    __bf16* Qs   = (__bf16*)alloc(16777216);   // (32,2048,128)
    __bf16* Ks   = (__bf16*)alloc(4194304);    // (8,2048,128)
    __bf16* Vts  = (__bf16*)alloc(4194304);    // (8,128,2048)
    float*  cosT = (float*)alloc(524288);
    float*  sinT = (float*)alloc(524288);
    __bf16* Yb = xb;                            // alias: xb dead after QKV GEMM

    prolog_kernel<<<18944, 256, 0, stream>>>(x, wq, wk, wv, wo, xb, Wall, cosT, sinT);
    gemm_bt8<1><<<dim3(384), 512, 0, stream>>>(xb, Wall, qkv, 4096, 3072, 2048);
    scatter_vt_kernel<<<3072, 256, 0, stream>>>(qkv, cosT, sinT, Qs, Ks, Vts);
    attn_kernel<<<dim3(512), 256, 0, stream>>>(Qs, Ks, Vts, Yb);
    gemm_bt<0><<<dim3(32 * 16), 256, 0, stream>>>(Yb, wob, out, 4096, 2048, 2048);
}

// Round 26
// 158.851 us; speedup vs baseline: 1.1965x; 1.1965x over previous
//
#include <hip/hip_runtime.h>
#include <hip/hip_bf16.h>

typedef __bf16 bf16x8 __attribute__((ext_vector_type(8)));
typedef __bf16 bf16x4 __attribute__((ext_vector_type(4)));
typedef float  f32x4  __attribute__((ext_vector_type(4)));
typedef float  f32x16 __attribute__((ext_vector_type(16)));
typedef unsigned int uint4v __attribute__((ext_vector_type(4)));

#define NB     2
#define TT     2048
#define CC     2048
#define NH     16
#define NKV    4
#define HD     128
#define WIN    1024
#define SINKN  4
// Q pre-scale folds 1/sqrt(128) AND log2(e): softmax runs in exp2 domain.
#define QSCALE2 (0.08838834764831845f * 1.44269504088896340f)

// ---- async global->LDS, 16B per lane; LDS dest is wave-uniform base (HW adds lane*16)
__device__ __forceinline__ void lds_load16(const void* g, void* l) {
    __builtin_amdgcn_global_load_lds(
        (__attribute__((address_space(1))) void*)const_cast<void*>(g),
        (__attribute__((address_space(3))) void*)l, 16, 0, 0);
}

__device__ __forceinline__ unsigned pack2bf(float a, float b) {
    __bf16 x = (__bf16)a, y = (__bf16)b;
    unsigned short ux = __builtin_bit_cast(unsigned short, x);
    unsigned short uy = __builtin_bit_cast(unsigned short, y);
    return (unsigned)ux | ((unsigned)uy << 16);
}

__device__ __forceinline__ float fast_exp2(float x) {   // v_exp_f32 = 2^x
    float r;
    asm("v_exp_f32 %0, %1" : "=v"(r) : "v"(x));
    return r;
}

// ===================== fused prologue: cvt x, cvt W, rope tables ============
__global__ void prolog_kernel(const float* __restrict__ x,
                              const float* __restrict__ wq, const float* __restrict__ wk,
                              const float* __restrict__ wv, const float* __restrict__ wo,
                              __bf16* __restrict__ xb, __bf16* __restrict__ Wall,
                              float* __restrict__ cosT, float* __restrict__ sinT) {
    const int g = blockIdx.x * 256 + threadIdx.x;
    if (g < 2097152) {                       // x -> bf16
        const int idx = g * 4;
        const float4 v = *(const float4*)(x + idx);
        bf16x4 o;
        o[0] = (__bf16)v.x; o[1] = (__bf16)v.y; o[2] = (__bf16)v.z; o[3] = (__bf16)v.w;
        *(bf16x4*)(xb + idx) = o;
    } else if (g < 4718592) {                // weights -> bf16 (contiguous Wall|wob)
        const int idx = (g - 2097152) * 4;
        const float* src; int off;
        if (idx < 4194304)      { src = wq; off = idx; }
        else if (idx < 5242880) { src = wk; off = idx - 4194304; }
        else if (idx < 6291456) { src = wv; off = idx - 5242880; }
        else                    { src = wo; off = idx - 6291456; }
        const float4 v = *(const float4*)(src + off);
        bf16x4 o;
        o[0] = (__bf16)v.x; o[1] = (__bf16)v.y; o[2] = (__bf16)v.z; o[3] = (__bf16)v.w;
        *(bf16x4*)(Wall + idx) = o;
    } else {                                 // rope tables
        const int i = g - 4718592;           // < 131072 = 2048*64
        const int t = i >> 6, d = i & 63;
        const float inv_freq = 1.0f / powf(10000.0f, (float)d * (1.0f / 64.0f));
        const float ang = (float)t * inv_freq;
        cosT[i] = cosf(ang);
        sinT[i] = sinf(ang);
    }
}

// ============ fused post-GEMM: RoPE scatter + V transpose ===================
__global__ void scatter_vt_kernel(const __bf16* __restrict__ qkv,
                                  const float* __restrict__ cosT,
                                  const float* __restrict__ sinT,
                                  __bf16* __restrict__ Qo,   // (B*NH, T, 128), pre-scaled (exp2 domain)
                                  __bf16* __restrict__ Ko,   // (B*NKV, T, 128)
                                  __bf16* __restrict__ Vt) { // (B*NKV, 128, T)
    __shared__ __bf16 tile[64][72];
    if (blockIdx.x < 2560) {
        const int job = blockIdx.x * 256 + threadIdx.x;
        int m, d8, base_off; __bf16* outp; float scale;
        if (job < 524288) {                 // Q
            m = job >> 7;
            const int pj = job & 127;
            const int hh = pj >> 3; d8 = pj & 7;
            base_off = hh * 128;
            const int b = m >> 11, t = m & 2047;
            outp = Qo + ((size_t)(b * NH + hh) * TT + t) * HD + d8 * 8;
            scale = QSCALE2;
        } else {                            // K
            const int j2 = job - 524288;
            m = j2 >> 5;
            const int pj = j2 & 31;
            const int g = pj >> 3; d8 = pj & 7;
            base_off = 2048 + g * 128;
            const int b = m >> 11, t = m & 2047;
            outp = Ko + ((size_t)(b * NKV + g) * TT + t) * HD + d8 * 8;
            scale = 1.0f;
        }
        const int t = m & 2047;
        const __bf16* row = qkv + (size_t)m * 3072 + base_off + d8 * 8;
        const bf16x8 x1 = *(const bf16x8*)row;
        const bf16x8 x2 = *(const bf16x8*)(row + 64);
        const float4 c0 = *(const float4*)(cosT + t * 64 + d8 * 8);
        const float4 c1 = *(const float4*)(cosT + t * 64 + d8 * 8 + 4);
        const float4 s0 = *(const float4*)(sinT + t * 64 + d8 * 8);
        const float4 s1 = *(const float4*)(sinT + t * 64 + d8 * 8 + 4);
        const float cs[8] = {c0.x, c0.y, c0.z, c0.w, c1.x, c1.y, c1.z, c1.w};
        const float sn[8] = {s0.x, s0.y, s0.z, s0.w, s1.x, s1.y, s1.z, s1.w};
        bf16x8 o1, o2;
#pragma unroll
        for (int e = 0; e < 8; ++e) {
            const float a = (float)x1[e], bb = (float)x2[e];
            o1[e] = (__bf16)((a * cs[e] - bb * sn[e]) * scale);
            o2[e] = (__bf16)((bb * cs[e] + a * sn[e]) * scale);
        }
        *(bf16x8*)outp = o1;
        *(bf16x8*)(outp + 64) = o2;
    } else {
        const int idx2 = blockIdx.x - 2560;       // old (32,2,8) grid flattened
        const int t0 = (idx2 & 31) << 6, d0 = ((idx2 >> 5) & 1) << 6, bkv = idx2 >> 6;
        const int b = bkv >> 2, g = bkv & 3;
        const int r = threadIdx.x >> 2, cg = threadIdx.x & 3;
        const __bf16* src = qkv + (size_t)(b * TT + t0 + r) * 3072 + 2560 + g * 128 + d0 + cg * 16;
        *(bf16x8*)&tile[r][cg * 16]     = *(const bf16x8*)src;
        *(bf16x8*)&tile[r][cg * 16 + 8] = *(const bf16x8*)(src + 8);
        __syncthreads();
        __bf16* dst = Vt + ((size_t)bkv * HD + d0 + r) * TT + t0 + cg * 16;
        bf16x8 o0, o1;
#pragma unroll
        for (int c2 = 0; c2 < 8; ++c2) {
            o0[c2] = tile[cg * 16 + c2][r];
            o1[c2] = tile[cg * 16 + 8 + c2][r];
        }
        *(bf16x8*)dst = o0;
        *(bf16x8*)(dst + 8) = o1;
    }
}

// ============ GEMM-8W-192: BM=256 BN=192 BK=64, 2-phase, dbuf, T1 ===========
// Exact 256-block fill for 4096x3072 (16 x 16). 8 waves as 2(M)x4(N); wave
// owns 128x48 of C.
template <int OUT_BF16>
__global__ __launch_bounds__(512, 2) void gemm_bt8(const __bf16* __restrict__ A,
                                                   const __bf16* __restrict__ Bm,
                                                   void* __restrict__ C,
                                                   int M, int N, int K) {
    __shared__ __align__(16) __bf16 lA[2][256 * 64];   // 2 x 32KB
    __shared__ __align__(16) __bf16 lB[2][192 * 64];   // 2 x 24KB
    const int tid = threadIdx.x;
    const int lane = tid & 63;
    const int w = tid >> 6;
    const int wm = w >> 2, wn = w & 3;                 // wave tile: rows wm*128, cols wn*48
    const int nbn = N / 192;
    const int nwg = (M >> 8) * nbn;
    const int chunk = nwg >> 3;                        // nwg % 8 == 0 (256)
    const int swz = (blockIdx.x & 7) * chunk + (blockIdx.x >> 3);
    const int bm = swz / nbn, bn = swz % nbn;
    const int m0 = bm << 8, n0 = bn * 192;
    const int lr = lane & 15, lh = lane >> 4;
    const int NT = K >> 6;

    auto stageA = [&](int kt, int buf, int i) {        // i in 0..3 (32KB)
        const int d = i * 8192 + tid * 16;
        const int row = d >> 7;
        const int colb = (d & 127) ^ ((row & 7) << 4);
        lds_load16(A + (size_t)(m0 + row) * K + kt * 64 + (colb >> 1),
                   (char*)lA[buf] + i * 8192 + w * 1024);
    };
    auto stageB = [&](int kt, int buf, int i) {        // i in 0..2 (24KB)
        const int d = i * 8192 + tid * 16;
        const int row = d >> 7;                        // 0..191
        const int colb = (d & 127) ^ ((row & 7) << 4);
        lds_load16(Bm + (size_t)(n0 + row) * K + kt * 64 + (colb >> 1),
                   (char*)lB[buf] + i * 8192 + w * 1024);
    };

    f32x4 acc[8][3] = {};

#pragma unroll
    for (int i = 0; i < 4; ++i) stageA(0, 0, i);
#pragma unroll
    for (int i = 0; i < 3; ++i) stageB(0, 0, i);
    asm volatile("s_waitcnt vmcnt(0)" ::: "memory");
    __syncthreads();

    for (int kt = 0; kt < NT; ++kt) {
        const int cur = kt & 1, nxt = cur ^ 1;
        const bool pf = (kt + 1 < NT);
        const char* bA = (const char*)lA[cur];
        const char* bB = (const char*)lB[cur];

        bf16x8 aF[4][2], bf3[3][2];
        // ---- phase 0: A row-half 0 (mf 0-3) x all B (nf 0-2); issue stageA ----
#pragma unroll
        for (int mf = 0; mf < 4; ++mf)
#pragma unroll
            for (int ks = 0; ks < 2; ++ks) {
                const int row = wm * 128 + mf * 16 + lr;
                const int cb = (ks * 64 + lh * 16) ^ ((row & 7) << 4);
                aF[mf][ks] = *(const bf16x8*)(bA + row * 128 + cb);
            }
#pragma unroll
        for (int nf = 0; nf < 3; ++nf)
#pragma unroll
            for (int ks = 0; ks < 2; ++ks) {
                const int row = wn * 48 + nf * 16 + lr;
                const int cb = (ks * 64 + lh * 16) ^ ((row & 7) << 4);
                bf3[nf][ks] = *(const bf16x8*)(bB + row * 128 + cb);
            }
        if (pf) { stageA(kt + 1, nxt, 0); stageA(kt + 1, nxt, 1); stageA(kt + 1, nxt, 2); stageA(kt + 1, nxt, 3); }
        __builtin_amdgcn_s_setprio(1);
#pragma unroll
        for (int mf = 0; mf < 4; ++mf)
#pragma unroll
            for (int nf = 0; nf < 3; ++nf)
#pragma unroll
                for (int ks = 0; ks < 2; ++ks)
                    acc[mf][nf] = __builtin_amdgcn_mfma_f32_16x16x32_bf16(aF[mf][ks], bf3[nf][ks], acc[mf][nf], 0, 0, 0);
        __builtin_amdgcn_s_setprio(0);

        // ---- phase 1: A row-half 1 (mf 4-7) x all B; issue stageB ----
#pragma unroll
        for (int mf = 0; mf < 4; ++mf)
#pragma unroll
            for (int ks = 0; ks < 2; ++ks) {
                const int row = wm * 128 + 64 + mf * 16 + lr;
                const int cb = (ks * 64 + lh * 16) ^ ((row & 7) << 4);
                aF[mf][ks] = *(const bf16x8*)(bA + row * 128 + cb);
            }
        if (pf) { stageB(kt + 1, nxt, 0); stageB(kt + 1, nxt, 1); stageB(kt + 1, nxt, 2); }
        __builtin_amdgcn_s_setprio(1);
#pragma unroll
        for (int mf = 0; mf < 4; ++mf)
#pragma unroll
            for (int nf = 0; nf < 3; ++nf)
#pragma unroll
                for (int ks = 0; ks < 2; ++ks)
                    acc[mf + 4][nf] = __builtin_amdgcn_mfma_f32_16x16x32_bf16(aF[mf][ks], bf3[nf][ks], acc[mf + 4][nf], 0, 0, 0);
        __builtin_amdgcn_s_setprio(0);

        asm volatile("s_waitcnt vmcnt(0)" ::: "memory");
        __syncthreads();
    }

    // ---- epilogue: C layout col=lr, row=lh*4+r ----
#pragma unroll
    for (int mf = 0; mf < 8; ++mf)
#pragma unroll
        for (int nf = 0; nf < 3; ++nf)
#pragma unroll
            for (int r = 0; r < 4; ++r) {
                const size_t row = m0 + wm * 128 + mf * 16 + lh * 4 + r;
                const size_t col = n0 + wn * 48 + nf * 16 + lr;
                if (OUT_BF16) ((__bf16*)C)[row * N + col] = (__bf16)acc[mf][nf][r];
                else          ((float*)C)[row * N + col]  = acc[mf][nf][r];
            }
}

// ====== GEMM-4W (out-proj): 128x128, BK=64, XOR-swizzled, dbuf, T1 ==========
template <int OUT_BF16>
__global__ __launch_bounds__(256, 2) void gemm_bt(const __bf16* __restrict__ A,
                                                  const __bf16* __restrict__ Bm,
                                                  void* __restrict__ C,
                                                  int M, int N, int K) {
    __shared__ __align__(16) __bf16 lA[2][128 * 64];   // 2 x 16KB
    __shared__ __align__(16) __bf16 lB[2][128 * 64];   // 2 x 16KB
    const int tid = threadIdx.x;
    const int lane = tid & 63;
    const int w = tid >> 6;
    const int wr = w >> 1, wc = w & 1;
    const int nbn = N >> 7;
    const int nwg = (M >> 7) * nbn;
    const int chunk = nwg >> 3;                        // nwg % 8 == 0 (512)
    const int swz = (blockIdx.x & 7) * chunk + (blockIdx.x >> 3);
    const int bm = swz / nbn, bn = swz % nbn;
    const int m0 = bm << 7, n0 = bn << 7;
    const int lr = lane & 15, lh = lane >> 4;
    f32x4 acc[4][4] = {};

    auto stage = [&](int k0, int buf) {
#pragma unroll
        for (int i = 0; i < 4; ++i) {                  // 256 thr x 16B = 32 rows/chunk
            const int d = i * 4096 + tid * 16;
            const int row = d >> 7;
            const int colb = (d & 127) ^ ((row & 7) << 4);
            lds_load16(A + (size_t)(m0 + row) * K + k0 + (colb >> 1),
                       (char*)lA[buf] + i * 4096 + w * 1024);
            lds_load16(Bm + (size_t)(n0 + row) * K + k0 + (colb >> 1),
                       (char*)lB[buf] + i * 4096 + w * 1024);
        }
    };

    stage(0, 0);
    asm volatile("s_waitcnt vmcnt(0)" ::: "memory");
    __syncthreads();

    const int NT = K >> 6;
    for (int kt = 0; kt < NT; ++kt) {
        const int buf = kt & 1;
        if (kt + 1 < NT) stage((kt + 1) << 6, buf ^ 1);   // prefetch before compute

        const char* bA = (const char*)lA[buf];
        const char* bB = (const char*)lB[buf];
        bf16x8 af[4][2], bfr[4][2];
#pragma unroll
        for (int t = 0; t < 4; ++t)
#pragma unroll
            for (int ks = 0; ks < 2; ++ks) {
                const int rowa = wr * 64 + t * 16 + lr;
                const int cba = (ks * 64 + lh * 16) ^ ((rowa & 7) << 4);
                af[t][ks] = *(const bf16x8*)(bA + rowa * 128 + cba);
                const int rowb = wc * 64 + t * 16 + lr;
                const int cbb = (ks * 64 + lh * 16) ^ ((rowb & 7) << 4);
                bfr[t][ks] = *(const bf16x8*)(bB + rowb * 128 + cbb);
            }
#pragma unroll
        for (int mt = 0; mt < 4; ++mt)
#pragma unroll
            for (int nt = 0; nt < 4; ++nt)
#pragma unroll
                for (int ks = 0; ks < 2; ++ks)
                    acc[mt][nt] = __builtin_amdgcn_mfma_f32_16x16x32_bf16(af[mt][ks], bfr[nt][ks], acc[mt][nt], 0, 0, 0);

        asm volatile("s_waitcnt vmcnt(0)" ::: "memory");
        __syncthreads();
    }

    const int r0 = (lane >> 4) * 4;
#pragma unroll
    for (int mt = 0; mt < 4; ++mt)
#pragma unroll
        for (int nt = 0; nt < 4; ++nt)
#pragma unroll
            for (int r = 0; r < 4; ++r) {
                const size_t row = m0 + wr * 64 + mt * 16 + r0 + r;
                const size_t col = n0 + wc * 64 + nt * 16 + lr;
                if (OUT_BF16) ((__bf16*)C)[row * N + col] = (__bf16)acc[mt][nt][r];
                else          ((float*)C)[row * N + col]  = acc[mt][nt][r];
            }
}

// ============================== flash attention =============================
// R19-exact (best measured: 55.2 us): 32x32x16 MFMA, block = 256 thr = 4
// waves = 4 heads; each wave computes all 32 q-rows of its head. XCD-pinned.
__global__ __launch_bounds__(256, 2) void attn_kernel(const __bf16* __restrict__ Q,
                                                      const __bf16* __restrict__ Kg,
                                                      const __bf16* __restrict__ Vt,
                                                      __bf16* __restrict__ Y) {
    const int id = blockIdx.x;
    const int grp = id & 7;                     // -> XCD (dispatch round-robin)
    const int pos = id >> 3;                    // 0..63
    const int kv = grp & 3, b = grp >> 2;
    const int qt2 = 63 - pos;                   // LPT within XCD
    const int q0 = qt2 << 5;                    // 32 q-rows per block
    const int tid = threadIdx.x, lane = tid & 63, w = tid >> 6;
    const int l31 = lane & 31, hi = lane >> 5;
    const int h  = kv * 4 + w;                  // wave = head

    __shared__ __align__(16) __bf16 lK[64 * 128];   // 16KB [k][d] 256B rows
    __shared__ __align__(16) __bf16 lV[128 * 64];   // 16KB V^T [d][t] 128B rows

    // Q as B-fragments: qf[c] = Q[q0+l31][c*16 + hi*8 .. +8]
    bf16x8 qf[8];
    {
        const __bf16* Qb = Q + ((size_t)(b * NH + h) * TT + q0) * HD;
#pragma unroll
        for (int c = 0; c < 8; ++c)
            qf[c] = *(const bf16x8*)(Qb + l31 * HD + c * 16 + hi * 8);
    }

    f32x16 acc[4] = {};                         // O: col d = dt*32+l31, row q pattern
    float mrun = -1e30f, lrun = 0.f;
    const int iq = q0 + l31;                    // this lane's q (S-layout)

    const __bf16* Kb = Kg + (size_t)(b * NKV + kv) * TT * HD;
    const __bf16* Vb = Vt + (size_t)(b * NKV + kv) * HD * TT;
    const int jend = qt2 >> 1;
    const int jsw  = (q0 > WIN) ? ((q0 - WIN) >> 6) : 0;

    for (int jb = 0; jb <= jend; ++jb) {
        if (jb > 0 && jb < jsw) continue;       // fully-masked (keep sink jb=0)
        const int j0 = jb << 6;
        __syncthreads();
        // stage 32KB with 256 thr: 4 chunks K (16 rows each), 4 chunks V (32 rows)
#pragma unroll
        for (int i = 0; i < 4; ++i) {
            const int o = i * 4096 + tid * 16;
            {   // K [64][128]: 256B rows
                const int row = o >> 8;
                const int colb = (o & 255) ^ ((row & 7) << 4);
                lds_load16(Kb + (size_t)(j0 + row) * HD + (colb >> 1),
                           (char*)lK + i * 4096 + w * 1024);
            }
            {   // V^T [128][64]: 128B rows
                const int row = o >> 7;
                const int colb = (o & 127) ^ ((row & 7) << 4);
                lds_load16(Vb + (size_t)row * TT + j0 + (colb >> 1),
                           (char*)lV + i * 4096 + w * 1024);
            }
        }
        asm volatile("s_waitcnt vmcnt(0)" ::: "memory");
        __syncthreads();

        // ---- S^T = K Q^T : two 32x32 tiles (kt2), K over d in 8 slices ----
        f32x16 st[2];
#pragma unroll
        for (int kt2 = 0; kt2 < 2; ++kt2) {
            f32x16 s = {};
#pragma unroll
            for (int c = 0; c < 8; ++c) {
                const int row = kt2 * 32 + l31;
                const int cb = (c * 32 + hi * 16) ^ ((row & 7) << 4);
                const bf16x8 kf = *(const bf16x8*)((const char*)lK + row * 256 + cb);
                s = __builtin_amdgcn_mfma_f32_32x32x16_bf16(kf, qf[c], s, 0, 0, 0);
            }
            st[kt2] = s;
        }

        // ---- mask (q fixed per lane; k in reg pattern) ----
        const bool fullTile = (j0 + 63 <= q0) && (q0 + 31 - j0 <= WIN);
        if (!fullTile) {
#pragma unroll
            for (int kt2 = 0; kt2 < 2; ++kt2)
#pragma unroll
                for (int rr = 0; rr < 16; ++rr) {
                    const int j = j0 + kt2 * 32 + (rr & 3) + 8 * (rr >> 2) + 4 * hi;
                    const bool ok = (j <= iq) && ((iq - j <= WIN) || (j < SINKN));
                    if (!ok) st[kt2][rr] = -1e30f;
                }
        }

        // ---- row max: 31 in-lane + 1 shuffle (L/L+32 share q-col) ----
        float mx = st[0][0];
#pragma unroll
        for (int kt2 = 0; kt2 < 2; ++kt2)
#pragma unroll
            for (int rr = 0; rr < 16; ++rr) mx = fmaxf(mx, st[kt2][rr]);
        mx = fmaxf(mx, __shfl_xor(mx, 32, 64));

        // ---- defer-max (T13; 11.53 log2-units = 8 nats) ----
        if (!__all(mx - mrun <= 11.53f)) {
            const float mnew = fmaxf(mrun, mx);
            const float corr = fast_exp2(mrun - mnew);
            mrun = mnew;
            lrun *= corr;
#pragma unroll
            for (int rr = 0; rr < 16; ++rr) {
                const float cq = __shfl(corr, (rr & 3) + 8 * (rr >> 2) + 4 * hi, 64);
#pragma unroll
                for (int dt = 0; dt < 4; ++dt) acc[dt][rr] *= cq;
            }
        }

        // ---- P = 2^(S - m), row sum (partial per half, combined via xor32) ----
        float rsum = 0.f;
#pragma unroll
        for (int kt2 = 0; kt2 < 2; ++kt2)
#pragma unroll
            for (int rr = 0; rr < 16; ++rr) {
                const float p = fast_exp2(st[kt2][rr] - mrun);
                st[kt2][rr] = p;
                rsum += p;
            }
        rsum += __shfl_xor(rsum, 32, 64);
        lrun += rsum;

        // ---- P -> A-fragments pa[c] (k-slice c of 16): lane<->lane+32 swap ----
        bf16x8 pa[4];
#pragma unroll
        for (int c = 0; c < 4; ++c) {
            const int kt2 = c >> 1, g = c & 1, base = 8 * g;
            const unsigned u1a = pack2bf(st[kt2][base + 0], st[kt2][base + 1]);
            const unsigned u1b = pack2bf(st[kt2][base + 2], st[kt2][base + 3]);
            const unsigned u2a = pack2bf(st[kt2][base + 4], st[kt2][base + 5]);
            const unsigned u2b = pack2bf(st[kt2][base + 6], st[kt2][base + 7]);
            const unsigned p1a = (unsigned)__shfl_xor((int)u1a, 32, 64);
            const unsigned p1b = (unsigned)__shfl_xor((int)u1b, 32, 64);
            const unsigned p2a = (unsigned)__shfl_xor((int)u2a, 32, 64);
            const unsigned p2b = (unsigned)__shfl_xor((int)u2b, 32, 64);
            uint4v uv;
            uv[0] = hi ? p2a : u1a;
            uv[1] = hi ? p2b : u1b;
            uv[2] = hi ? u2a : p1a;
            uv[3] = hi ? u2b : p1b;
            pa[c] = __builtin_bit_cast(bf16x8, uv);
        }

        // ---- O += P V : 4 d-tiles x 4 k-slices ----
#pragma unroll
        for (int dt = 0; dt < 4; ++dt) {
            const int row = dt * 32 + l31;
            const int swzr = (row & 7) << 4;
#pragma unroll
            for (int c = 0; c < 4; ++c) {
                const int cb = (c * 32 + hi * 16) ^ swzr;
                const bf16x8 vf = *(const bf16x8*)((const char*)lV + row * 128 + cb);
                acc[dt] = __builtin_amdgcn_mfma_f32_32x32x16_bf16(pa[c], vf, acc[dt], 0, 0, 0);
            }
        }
    }

    // ---- epilogue: q = (rr&3)+8*(rr>>2)+4hi, d = dt*32+l31 ----
    const float inv = 1.f / lrun;
    float invq[16];
#pragma unroll
    for (int rr = 0; rr < 16; ++rr)
        invq[rr] = __shfl(inv, (rr & 3) + 8 * (rr >> 2) + 4 * hi, 64);
#pragma unroll
    for (int dt = 0; dt < 4; ++dt)
#pragma unroll
        for (int rr = 0; rr < 16; ++rr) {
            const int qrow = (rr & 3) + 8 * (rr >> 2) + 4 * hi;
            Y[((size_t)b * TT + q0 + qrow) * CC + h * HD + dt * 32 + l31] =
                (__bf16)(acc[dt][rr] * invq[rr]);
        }
}

// ================================ launch ====================================
extern "C" void kernel_launch(void* const* d_in, const int* in_sizes, int n_in,
                              void* d_out, int out_size, void* d_ws, size_t ws_size,
                              hipStream_t stream) {
    const float* x  = (const float*)d_in[0];
    const float* wq = (const float*)d_in[1];
    const float* wk = (const float*)d_in[2];
    const float* wv = (const float*)d_in[3];
    const float* wo = (const float*)d_in[4];
    float* out = (float*)d_out;

    char* ws = (char*)d_ws;
    size_t off = 0;
    auto alloc = [&](size_t bytes) { char* p = ws + off; off += bytes; return p; };
    __bf16* xb   = (__bf16*)alloc(16777216);   // x bf16 (4096x2048); reused as Y after attn
    __bf16* Wall = (__bf16*)alloc(12582912);   // [wq;wk;wv] (3072x2048)
    __bf16* wob  = (__bf16*)alloc(8388608);    // wo (2048x2048), contiguous after Wall
    __bf16* qkv  = (__bf16*)alloc(25165824);   // (4096x3072)
    __bf16* Qs   = (__bf16*)alloc(16777216);   // (32,2048,128)
    __bf16* Ks   = (__bf16*)alloc(4194304);    // (8,2048,128)
    __bf16* Vts  = (__bf16*)alloc(4194304);    // (8,128,2048)
    float*  cosT = (float*)alloc(524288);
    float*  sinT = (float*)alloc(524288);
    __bf16* Yb = xb;                            // alias: xb dead after QKV GEMM

    prolog_kernel<<<18944, 256, 0, stream>>>(x, wq, wk, wv, wo, xb, Wall, cosT, sinT);
    gemm_bt8<1><<<dim3(256), 512, 0, stream>>>(xb, Wall, qkv, 4096, 3072, 2048);
    scatter_vt_kernel<<<3072, 256, 0, stream>>>(qkv, cosT, sinT, Qs, Ks, Vts);
    attn_kernel<<<dim3(512), 256, 0, stream>>>(Qs, Ks, Vts, Yb);
    gemm_bt<0><<<dim3(32 * 16), 256, 0, stream>>>(Yb, wob, out, 4096, 2048, 2048);
}

// Round 27
// 158.638 us; speedup vs baseline: 1.1981x; 1.0013x over previous
//
#include <hip/hip_runtime.h>
#include <hip/hip_bf16.h>

typedef __bf16 bf16x8 __attribute__((ext_vector_type(8)));
typedef __bf16 bf16x4 __attribute__((ext_vector_type(4)));
typedef float  f32x4  __attribute__((ext_vector_type(4)));
typedef float  f32x16 __attribute__((ext_vector_type(16)));
typedef unsigned int uint4v __attribute__((ext_vector_type(4)));

#define NB     2
#define TT     2048
#define CC     2048
#define NH     16
#define NKV    4
#define HD     128
#define WIN    1024
#define SINKN  4
// Q pre-scale folds 1/sqrt(128) AND log2(e): softmax runs in exp2 domain.
#define QSCALE2 (0.08838834764831845f * 1.44269504088896340f)

// ---- async global->LDS, 16B per lane; LDS dest is wave-uniform base (HW adds lane*16)
__device__ __forceinline__ void lds_load16(const void* g, void* l) {
    __builtin_amdgcn_global_load_lds(
        (__attribute__((address_space(1))) void*)const_cast<void*>(g),
        (__attribute__((address_space(3))) void*)l, 16, 0, 0);
}

__device__ __forceinline__ unsigned pack2bf(float a, float b) {
    __bf16 x = (__bf16)a, y = (__bf16)b;
    unsigned short ux = __builtin_bit_cast(unsigned short, x);
    unsigned short uy = __builtin_bit_cast(unsigned short, y);
    return (unsigned)ux | ((unsigned)uy << 16);
}

__device__ __forceinline__ float fast_exp2(float x) {   // v_exp_f32 = 2^x
    float r;
    asm("v_exp_f32 %0, %1" : "=v"(r) : "v"(x));
    return r;
}

// ===================== fused prologue: cvt x, cvt W, rope tables ============
__global__ void prolog_kernel(const float* __restrict__ x,
                              const float* __restrict__ wq, const float* __restrict__ wk,
                              const float* __restrict__ wv, const float* __restrict__ wo,
                              __bf16* __restrict__ xb, __bf16* __restrict__ Wall,
                              float* __restrict__ cosT, float* __restrict__ sinT) {
    const int g = blockIdx.x * 256 + threadIdx.x;
    if (g < 2097152) {                       // x -> bf16
        const int idx = g * 4;
        const float4 v = *(const float4*)(x + idx);
        bf16x4 o;
        o[0] = (__bf16)v.x; o[1] = (__bf16)v.y; o[2] = (__bf16)v.z; o[3] = (__bf16)v.w;
        *(bf16x4*)(xb + idx) = o;
    } else if (g < 4718592) {                // weights -> bf16 (contiguous Wall|wob)
        const int idx = (g - 2097152) * 4;
        const float* src; int off;
        if (idx < 4194304)      { src = wq; off = idx; }
        else if (idx < 5242880) { src = wk; off = idx - 4194304; }
        else if (idx < 6291456) { src = wv; off = idx - 5242880; }
        else                    { src = wo; off = idx - 6291456; }
        const float4 v = *(const float4*)(src + off);
        bf16x4 o;
        o[0] = (__bf16)v.x; o[1] = (__bf16)v.y; o[2] = (__bf16)v.z; o[3] = (__bf16)v.w;
        *(bf16x4*)(Wall + idx) = o;
    } else {                                 // rope tables
        const int i = g - 4718592;           // < 131072 = 2048*64
        const int t = i >> 6, d = i & 63;
        const float inv_freq = 1.0f / powf(10000.0f, (float)d * (1.0f / 64.0f));
        const float ang = (float)t * inv_freq;
        cosT[i] = cosf(ang);
        sinT[i] = sinf(ang);
    }
}

// ============ fused post-GEMM: RoPE scatter + V transpose ===================
__global__ void scatter_vt_kernel(const __bf16* __restrict__ qkv,
                                  const float* __restrict__ cosT,
                                  const float* __restrict__ sinT,
                                  __bf16* __restrict__ Qo,   // (B*NH, T, 128), pre-scaled (exp2 domain)
                                  __bf16* __restrict__ Ko,   // (B*NKV, T, 128)
                                  __bf16* __restrict__ Vt) { // (B*NKV, 128, T)
    __shared__ __bf16 tile[64][72];
    if (blockIdx.x < 2560) {
        const int job = blockIdx.x * 256 + threadIdx.x;
        int m, d8, base_off; __bf16* outp; float scale;
        if (job < 524288) {                 // Q
            m = job >> 7;
            const int pj = job & 127;
            const int hh = pj >> 3; d8 = pj & 7;
            base_off = hh * 128;
            const int b = m >> 11, t = m & 2047;
            outp = Qo + ((size_t)(b * NH + hh) * TT + t) * HD + d8 * 8;
            scale = QSCALE2;
        } else {                            // K
            const int j2 = job - 524288;
            m = j2 >> 5;
            const int pj = j2 & 31;
            const int g = pj >> 3; d8 = pj & 7;
            base_off = 2048 + g * 128;
            const int b = m >> 11, t = m & 2047;
            outp = Ko + ((size_t)(b * NKV + g) * TT + t) * HD + d8 * 8;
            scale = 1.0f;
        }
        const int t = m & 2047;
        const __bf16* row = qkv + (size_t)m * 3072 + base_off + d8 * 8;
        const bf16x8 x1 = *(const bf16x8*)row;
        const bf16x8 x2 = *(const bf16x8*)(row + 64);
        const float4 c0 = *(const float4*)(cosT + t * 64 + d8 * 8);
        const float4 c1 = *(const float4*)(cosT + t * 64 + d8 * 8 + 4);
        const float4 s0 = *(const float4*)(sinT + t * 64 + d8 * 8);
        const float4 s1 = *(const float4*)(sinT + t * 64 + d8 * 8 + 4);
        const float cs[8] = {c0.x, c0.y, c0.z, c0.w, c1.x, c1.y, c1.z, c1.w};
        const float sn[8] = {s0.x, s0.y, s0.z, s0.w, s1.x, s1.y, s1.z, s1.w};
        bf16x8 o1, o2;
#pragma unroll
        for (int e = 0; e < 8; ++e) {
            const float a = (float)x1[e], bb = (float)x2[e];
            o1[e] = (__bf16)((a * cs[e] - bb * sn[e]) * scale);
            o2[e] = (__bf16)((bb * cs[e] + a * sn[e]) * scale);
        }
        *(bf16x8*)outp = o1;
        *(bf16x8*)(outp + 64) = o2;
    } else {
        const int idx2 = blockIdx.x - 2560;       // old (32,2,8) grid flattened
        const int t0 = (idx2 & 31) << 6, d0 = ((idx2 >> 5) & 1) << 6, bkv = idx2 >> 6;
        const int b = bkv >> 2, g = bkv & 3;
        const int r = threadIdx.x >> 2, cg = threadIdx.x & 3;
        const __bf16* src = qkv + (size_t)(b * TT + t0 + r) * 3072 + 2560 + g * 128 + d0 + cg * 16;
        *(bf16x8*)&tile[r][cg * 16]     = *(const bf16x8*)src;
        *(bf16x8*)&tile[r][cg * 16 + 8] = *(const bf16x8*)(src + 8);
        __syncthreads();
        __bf16* dst = Vt + ((size_t)bkv * HD + d0 + r) * TT + t0 + cg * 16;
        bf16x8 o0, o1;
#pragma unroll
        for (int c2 = 0; c2 < 8; ++c2) {
            o0[c2] = tile[cg * 16 + c2][r];
            o1[c2] = tile[cg * 16 + 8 + c2][r];
        }
        *(bf16x8*)dst = o0;
        *(bf16x8*)(dst + 8) = o1;
    }
}

// ============ GEMM-8W-192: BM=256 BN=192 BK=64, 2-phase, dbuf, T1 ===========
// Exact 256-block fill for 4096x3072 (16 x 16). 8 waves as 2(M)x4(N); wave
// owns 128x48 of C.
template <int OUT_BF16>
__global__ __launch_bounds__(512, 2) void gemm_bt8(const __bf16* __restrict__ A,
                                                   const __bf16* __restrict__ Bm,
                                                   void* __restrict__ C,
                                                   int M, int N, int K) {
    __shared__ __align__(16) __bf16 lA[2][256 * 64];   // 2 x 32KB
    __shared__ __align__(16) __bf16 lB[2][192 * 64];   // 2 x 24KB
    const int tid = threadIdx.x;
    const int lane = tid & 63;
    const int w = tid >> 6;
    const int wm = w >> 2, wn = w & 3;                 // wave tile: rows wm*128, cols wn*48
    const int nbn = N / 192;
    const int nwg = (M >> 8) * nbn;
    const int chunk = nwg >> 3;                        // nwg % 8 == 0 (256)
    const int swz = (blockIdx.x & 7) * chunk + (blockIdx.x >> 3);
    const int bm = swz / nbn, bn = swz % nbn;
    const int m0 = bm << 8, n0 = bn * 192;
    const int lr = lane & 15, lh = lane >> 4;
    const int NT = K >> 6;

    auto stageA = [&](int kt, int buf, int i) {        // i in 0..3 (32KB)
        const int d = i * 8192 + tid * 16;
        const int row = d >> 7;
        const int colb = (d & 127) ^ ((row & 7) << 4);
        lds_load16(A + (size_t)(m0 + row) * K + kt * 64 + (colb >> 1),
                   (char*)lA[buf] + i * 8192 + w * 1024);
    };
    auto stageB = [&](int kt, int buf, int i) {        // i in 0..2 (24KB)
        const int d = i * 8192 + tid * 16;
        const int row = d >> 7;                        // 0..191
        const int colb = (d & 127) ^ ((row & 7) << 4);
        lds_load16(Bm + (size_t)(n0 + row) * K + kt * 64 + (colb >> 1),
                   (char*)lB[buf] + i * 8192 + w * 1024);
    };

    f32x4 acc[8][3] = {};

#pragma unroll
    for (int i = 0; i < 4; ++i) stageA(0, 0, i);
#pragma unroll
    for (int i = 0; i < 3; ++i) stageB(0, 0, i);
    asm volatile("s_waitcnt vmcnt(0)" ::: "memory");
    __syncthreads();

    for (int kt = 0; kt < NT; ++kt) {
        const int cur = kt & 1, nxt = cur ^ 1;
        const bool pf = (kt + 1 < NT);
        const char* bA = (const char*)lA[cur];
        const char* bB = (const char*)lB[cur];

        bf16x8 aF[4][2], bf3[3][2];
        // ---- phase 0: A row-half 0 (mf 0-3) x all B (nf 0-2); issue stageA ----
#pragma unroll
        for (int mf = 0; mf < 4; ++mf)
#pragma unroll
            for (int ks = 0; ks < 2; ++ks) {
                const int row = wm * 128 + mf * 16 + lr;
                const int cb = (ks * 64 + lh * 16) ^ ((row & 7) << 4);
                aF[mf][ks] = *(const bf16x8*)(bA + row * 128 + cb);
            }
#pragma unroll
        for (int nf = 0; nf < 3; ++nf)
#pragma unroll
            for (int ks = 0; ks < 2; ++ks) {
                const int row = wn * 48 + nf * 16 + lr;
                const int cb = (ks * 64 + lh * 16) ^ ((row & 7) << 4);
                bf3[nf][ks] = *(const bf16x8*)(bB + row * 128 + cb);
            }
        if (pf) { stageA(kt + 1, nxt, 0); stageA(kt + 1, nxt, 1); stageA(kt + 1, nxt, 2); stageA(kt + 1, nxt, 3); }
        __builtin_amdgcn_s_setprio(1);
#pragma unroll
        for (int mf = 0; mf < 4; ++mf)
#pragma unroll
            for (int nf = 0; nf < 3; ++nf)
#pragma unroll
                for (int ks = 0; ks < 2; ++ks)
                    acc[mf][nf] = __builtin_amdgcn_mfma_f32_16x16x32_bf16(aF[mf][ks], bf3[nf][ks], acc[mf][nf], 0, 0, 0);
        __builtin_amdgcn_s_setprio(0);

        // ---- phase 1: A row-half 1 (mf 4-7) x all B; issue stageB ----
#pragma unroll
        for (int mf = 0; mf < 4; ++mf)
#pragma unroll
            for (int ks = 0; ks < 2; ++ks) {
                const int row = wm * 128 + 64 + mf * 16 + lr;
                const int cb = (ks * 64 + lh * 16) ^ ((row & 7) << 4);
                aF[mf][ks] = *(const bf16x8*)(bA + row * 128 + cb);
            }
        if (pf) { stageB(kt + 1, nxt, 0); stageB(kt + 1, nxt, 1); stageB(kt + 1, nxt, 2); }
        __builtin_amdgcn_s_setprio(1);
#pragma unroll
        for (int mf = 0; mf < 4; ++mf)
#pragma unroll
            for (int nf = 0; nf < 3; ++nf)
#pragma unroll
                for (int ks = 0; ks < 2; ++ks)
                    acc[mf + 4][nf] = __builtin_amdgcn_mfma_f32_16x16x32_bf16(aF[mf][ks], bf3[nf][ks], acc[mf + 4][nf], 0, 0, 0);
        __builtin_amdgcn_s_setprio(0);

        asm volatile("s_waitcnt vmcnt(0)" ::: "memory");
        __syncthreads();
    }

    // ---- epilogue: C layout col=lr, row=lh*4+r ----
#pragma unroll
    for (int mf = 0; mf < 8; ++mf)
#pragma unroll
        for (int nf = 0; nf < 3; ++nf)
#pragma unroll
            for (int r = 0; r < 4; ++r) {
                const size_t row = m0 + wm * 128 + mf * 16 + lh * 4 + r;
                const size_t col = n0 + wn * 48 + nf * 16 + lr;
                if (OUT_BF16) ((__bf16*)C)[row * N + col] = (__bf16)acc[mf][nf][r];
                else          ((float*)C)[row * N + col]  = acc[mf][nf][r];
            }
}

// ====== GEMM-4W (out-proj): 128x128, BK=64, XOR-swizzled, dbuf, T1 ==========
template <int OUT_BF16>
__global__ __launch_bounds__(256, 2) void gemm_bt(const __bf16* __restrict__ A,
                                                  const __bf16* __restrict__ Bm,
                                                  void* __restrict__ C,
                                                  int M, int N, int K) {
    __shared__ __align__(16) __bf16 lA[2][128 * 64];   // 2 x 16KB
    __shared__ __align__(16) __bf16 lB[2][128 * 64];   // 2 x 16KB
    const int tid = threadIdx.x;
    const int lane = tid & 63;
    const int w = tid >> 6;
    const int wr = w >> 1, wc = w & 1;
    const int nbn = N >> 7;
    const int nwg = (M >> 7) * nbn;
    const int chunk = nwg >> 3;                        // nwg % 8 == 0 (512)
    const int swz = (blockIdx.x & 7) * chunk + (blockIdx.x >> 3);
    const int bm = swz / nbn, bn = swz % nbn;
    const int m0 = bm << 7, n0 = bn << 7;
    const int lr = lane & 15, lh = lane >> 4;
    f32x4 acc[4][4] = {};

    auto stage = [&](int k0, int buf) {
#pragma unroll
        for (int i = 0; i < 4; ++i) {                  // 256 thr x 16B = 32 rows/chunk
            const int d = i * 4096 + tid * 16;
            const int row = d >> 7;
            const int colb = (d & 127) ^ ((row & 7) << 4);
            lds_load16(A + (size_t)(m0 + row) * K + k0 + (colb >> 1),
                       (char*)lA[buf] + i * 4096 + w * 1024);
            lds_load16(Bm + (size_t)(n0 + row) * K + k0 + (colb >> 1),
                       (char*)lB[buf] + i * 4096 + w * 1024);
        }
    };

    stage(0, 0);
    asm volatile("s_waitcnt vmcnt(0)" ::: "memory");
    __syncthreads();

    const int NT = K >> 6;
    for (int kt = 0; kt < NT; ++kt) {
        const int buf = kt & 1;
        if (kt + 1 < NT) stage((kt + 1) << 6, buf ^ 1);   // prefetch before compute

        const char* bA = (const char*)lA[buf];
        const char* bB = (const char*)lB[buf];
        bf16x8 af[4][2], bfr[4][2];
#pragma unroll
        for (int t = 0; t < 4; ++t)
#pragma unroll
            for (int ks = 0; ks < 2; ++ks) {
                const int rowa = wr * 64 + t * 16 + lr;
                const int cba = (ks * 64 + lh * 16) ^ ((rowa & 7) << 4);
                af[t][ks] = *(const bf16x8*)(bA + rowa * 128 + cba);
                const int rowb = wc * 64 + t * 16 + lr;
                const int cbb = (ks * 64 + lh * 16) ^ ((rowb & 7) << 4);
                bfr[t][ks] = *(const bf16x8*)(bB + rowb * 128 + cbb);
            }
#pragma unroll
        for (int mt = 0; mt < 4; ++mt)
#pragma unroll
            for (int nt = 0; nt < 4; ++nt)
#pragma unroll
                for (int ks = 0; ks < 2; ++ks)
                    acc[mt][nt] = __builtin_amdgcn_mfma_f32_16x16x32_bf16(af[mt][ks], bfr[nt][ks], acc[mt][nt], 0, 0, 0);

        asm volatile("s_waitcnt vmcnt(0)" ::: "memory");
        __syncthreads();
    }

    const int r0 = (lane >> 4) * 4;
#pragma unroll
    for (int mt = 0; mt < 4; ++mt)
#pragma unroll
        for (int nt = 0; nt < 4; ++nt)
#pragma unroll
            for (int r = 0; r < 4; ++r) {
                const size_t row = m0 + wr * 64 + mt * 16 + r0 + r;
                const size_t col = n0 + wc * 64 + nt * 16 + lr;
                if (OUT_BF16) ((__bf16*)C)[row * N + col] = (__bf16)acc[mt][nt][r];
                else          ((float*)C)[row * N + col]  = acc[mt][nt][r];
            }
}

// ============================== flash attention =============================
// R19 structure + R11-proven counted-vmcnt double buffer: stage(next) into
// the other 32KB buffer BEFORE compute, s_waitcnt vmcnt(8) (waits current
// tile's 8 loads only), raw s_barrier + sched_barrier(0), compute, end raw
// barrier. LDS 64KB -> still 2 blocks/CU at 256 thr.
__global__ __launch_bounds__(256, 2) void attn_kernel(const __bf16* __restrict__ Q,
                                                      const __bf16* __restrict__ Kg,
                                                      const __bf16* __restrict__ Vt,
                                                      __bf16* __restrict__ Y) {
    const int id = blockIdx.x;
    const int grp = id & 7;                     // -> XCD (dispatch round-robin)
    const int pos = id >> 3;                    // 0..63
    const int kv = grp & 3, b = grp >> 2;
    const int qt2 = 63 - pos;                   // LPT within XCD
    const int q0 = qt2 << 5;                    // 32 q-rows per block
    const int tid = threadIdx.x, lane = tid & 63, w = tid >> 6;
    const int l31 = lane & 31, hi = lane >> 5;
    const int h  = kv * 4 + w;                  // wave = head

    __shared__ __align__(16) __bf16 lK[2][64 * 128];   // 2 x 16KB [k][d] 256B rows
    __shared__ __align__(16) __bf16 lV[2][128 * 64];   // 2 x 16KB V^T [d][t] 128B rows

    // Q as B-fragments: qf[c] = Q[q0+l31][c*16 + hi*8 .. +8]
    bf16x8 qf[8];
    {
        const __bf16* Qb = Q + ((size_t)(b * NH + h) * TT + q0) * HD;
#pragma unroll
        for (int c = 0; c < 8; ++c)
            qf[c] = *(const bf16x8*)(Qb + l31 * HD + c * 16 + hi * 8);
    }

    f32x16 acc[4] = {};                         // O: col d = dt*32+l31, row q pattern
    float mrun = -1e30f, lrun = 0.f;
    const int iq = q0 + l31;                    // this lane's q (S-layout)

    const __bf16* Kb = Kg + (size_t)(b * NKV + kv) * TT * HD;
    const __bf16* Vb = Vt + (size_t)(b * NKV + kv) * HD * TT;
    const int jend = qt2 >> 1;
    const int jsw  = (q0 > WIN) ? ((q0 - WIN) >> 6) : 0;
    const int jswe = (jsw < 1) ? 1 : jsw;
    const int nv   = (jend >= jswe) ? (jend - jswe + 2) : 1;   // {0} U [jswe..jend]

    // stage one 32KB tile (8 loads/thread: 4 chunks K + 4 chunks V)
    auto stage = [&](int jb, int buf) {
        const int j0s = jb << 6;
#pragma unroll
        for (int i = 0; i < 4; ++i) {
            const int o = i * 4096 + tid * 16;
            {   // K [64][128]: 256B rows, XOR-swizzled via global source
                const int row = o >> 8;
                const int colb = (o & 255) ^ ((row & 7) << 4);
                lds_load16(Kb + (size_t)(j0s + row) * HD + (colb >> 1),
                           (char*)lK[buf] + i * 4096 + w * 1024);
            }
            {   // V^T [128][64]: 128B rows
                const int row = o >> 7;
                const int colb = (o & 127) ^ ((row & 7) << 4);
                lds_load16(Vb + (size_t)row * TT + j0s + (colb >> 1),
                           (char*)lV[buf] + i * 4096 + w * 1024);
            }
        }
    };

    stage(0, 0);                                 // prologue: visited[0] -> buf 0

    for (int idx = 0; idx < nv; ++idx) {
        const int cur = idx & 1;
        const bool pf = (idx + 1 < nv);
        const int jb = (idx == 0) ? 0 : (jswe + idx - 1);
        const int j0 = jb << 6;

        if (pf) stage(jswe + idx, cur ^ 1);      // issue next tile (8 loads/thr)
        if (pf) asm volatile("s_waitcnt vmcnt(8)" ::: "memory");  // wait cur only
        else    asm volatile("s_waitcnt vmcnt(0)" ::: "memory");
        __builtin_amdgcn_s_barrier();            // raw: no vmcnt re-drain
        __builtin_amdgcn_sched_barrier(0);       // keep ds_reads below barrier

        const char* bK = (const char*)lK[cur];
        const char* bV = (const char*)lV[cur];

        // ---- S^T = K Q^T : two 32x32 tiles (kt2), K over d in 8 slices ----
        f32x16 st[2];
#pragma unroll
        for (int kt2 = 0; kt2 < 2; ++kt2) {
            f32x16 s = {};
#pragma unroll
            for (int c = 0; c < 8; ++c) {
                const int row = kt2 * 32 + l31;
                const int cb = (c * 32 + hi * 16) ^ ((row & 7) << 4);
                const bf16x8 kf = *(const bf16x8*)(bK + row * 256 + cb);
                s = __builtin_amdgcn_mfma_f32_32x32x16_bf16(kf, qf[c], s, 0, 0, 0);
            }
            st[kt2] = s;
        }

        // ---- mask (q fixed per lane; k in reg pattern) ----
        const bool fullTile = (j0 + 63 <= q0) && (q0 + 31 - j0 <= WIN);
        if (!fullTile) {
#pragma unroll
            for (int kt2 = 0; kt2 < 2; ++kt2)
#pragma unroll
                for (int rr = 0; rr < 16; ++rr) {
                    const int j = j0 + kt2 * 32 + (rr & 3) + 8 * (rr >> 2) + 4 * hi;
                    const bool ok = (j <= iq) && ((iq - j <= WIN) || (j < SINKN));
                    if (!ok) st[kt2][rr] = -1e30f;
                }
        }

        // ---- row max: 31 in-lane + 1 shuffle (L/L+32 share q-col) ----
        float mx = st[0][0];
#pragma unroll
        for (int kt2 = 0; kt2 < 2; ++kt2)
#pragma unroll
            for (int rr = 0; rr < 16; ++rr) mx = fmaxf(mx, st[kt2][rr]);
        mx = fmaxf(mx, __shfl_xor(mx, 32, 64));

        // ---- defer-max (T13; 11.53 log2-units = 8 nats) ----
        if (!__all(mx - mrun <= 11.53f)) {
            const float mnew = fmaxf(mrun, mx);
            const float corr = fast_exp2(mrun - mnew);
            mrun = mnew;
            lrun *= corr;
#pragma unroll
            for (int rr = 0; rr < 16; ++rr) {
                const float cq = __shfl(corr, (rr & 3) + 8 * (rr >> 2) + 4 * hi, 64);
#pragma unroll
                for (int dt = 0; dt < 4; ++dt) acc[dt][rr] *= cq;
            }
        }

        // ---- P = 2^(S - m), row sum (partial per half, combined via xor32) ----
        float rsum = 0.f;
#pragma unroll
        for (int kt2 = 0; kt2 < 2; ++kt2)
#pragma unroll
            for (int rr = 0; rr < 16; ++rr) {
                const float p = fast_exp2(st[kt2][rr] - mrun);
                st[kt2][rr] = p;
                rsum += p;
            }
        rsum += __shfl_xor(rsum, 32, 64);
        lrun += rsum;

        // ---- P -> A-fragments pa[c] (k-slice c of 16): lane<->lane+32 swap ----
        bf16x8 pa[4];
#pragma unroll
        for (int c = 0; c < 4; ++c) {
            const int kt2 = c >> 1, g = c & 1, base = 8 * g;
            const unsigned u1a = pack2bf(st[kt2][base + 0], st[kt2][base + 1]);
            const unsigned u1b = pack2bf(st[kt2][base + 2], st[kt2][base + 3]);
            const unsigned u2a = pack2bf(st[kt2][base + 4], st[kt2][base + 5]);
            const unsigned u2b = pack2bf(st[kt2][base + 6], st[kt2][base + 7]);
            const unsigned p1a = (unsigned)__shfl_xor((int)u1a, 32, 64);
            const unsigned p1b = (unsigned)__shfl_xor((int)u1b, 32, 64);
            const unsigned p2a = (unsigned)__shfl_xor((int)u2a, 32, 64);
            const unsigned p2b = (unsigned)__shfl_xor((int)u2b, 32, 64);
            uint4v uv;
            uv[0] = hi ? p2a : u1a;
            uv[1] = hi ? p2b : u1b;
            uv[2] = hi ? u2a : p1a;
            uv[3] = hi ? u2b : p1b;
            pa[c] = __builtin_bit_cast(bf16x8, uv);
        }

        // ---- O += P V : 4 d-tiles x 4 k-slices ----
#pragma unroll
        for (int dt = 0; dt < 4; ++dt) {
            const int row = dt * 32 + l31;
            const int swzr = (row & 7) << 4;
#pragma unroll
            for (int c = 0; c < 4; ++c) {
                const int cb = (c * 32 + hi * 16) ^ swzr;
                const bf16x8 vf = *(const bf16x8*)(bV + row * 128 + cb);
                acc[dt] = __builtin_amdgcn_mfma_f32_32x32x16_bf16(pa[c], vf, acc[dt], 0, 0, 0);
            }
        }

        if (pf) __builtin_amdgcn_s_barrier();    // buf[cur] free for next stage
    }

    // ---- epilogue: q = (rr&3)+8*(rr>>2)+4hi, d = dt*32+l31 ----
    const float inv = 1.f / lrun;
    float invq[16];
#pragma unroll
    for (int rr = 0; rr < 16; ++rr)
        invq[rr] = __shfl(inv, (rr & 3) + 8 * (rr >> 2) + 4 * hi, 64);
#pragma unroll
    for (int dt = 0; dt < 4; ++dt)
#pragma unroll
        for (int rr = 0; rr < 16; ++rr) {
            const int qrow = (rr & 3) + 8 * (rr >> 2) + 4 * hi;
            Y[((size_t)b * TT + q0 + qrow) * CC + h * HD + dt * 32 + l31] =
                (__bf16)(acc[dt][rr] * invq[rr]);
        }
}

// ================================ launch ====================================
extern "C" void kernel_launch(void* const* d_in, const int* in_sizes, int n_in,
                              void* d_out, int out_size, void* d_ws, size_t ws_size,
                              hipStream_t stream) {
    const float* x  = (const float*)d_in[0];
    const float* wq = (const float*)d_in[1];
    const float* wk = (const float*)d_in[2];
    const float* wv = (const float*)d_in[3];
    const float* wo = (const float*)d_in[4];
    float* out = (float*)d_out;

    char* ws = (char*)d_ws;
    size_t off = 0;
    auto alloc = [&](size_t bytes) { char* p = ws + off; off += bytes; return p; };
    __bf16* xb   = (__bf16*)alloc(16777216);   // x bf16 (4096x2048); reused as Y after attn
    __bf16* Wall = (__bf16*)alloc(12582912);   // [wq;wk;wv] (3072x2048)
    __bf16* wob  = (__bf16*)alloc(8388608);    // wo (2048x2048), contiguous after Wall
    __bf16* qkv  = (__bf16*)alloc(25165824);   // (4096x3072)
    __bf16* Qs   = (__bf16*)alloc(16777216);   // (32,2048,128)
    __bf16* Ks   = (__bf16*)alloc(4194304);    // (8,2048,128)
    __bf16* Vts  = (__bf16*)alloc(4194304);    // (8,128,2048)
    float*  cosT = (float*)alloc(524288);
    float*  sinT = (float*)alloc(524288);
    __bf16* Yb = xb;                            // alias: xb dead after QKV GEMM

    prolog_kernel<<<18944, 256, 0, stream>>>(x, wq, wk, wv, wo, xb, Wall, cosT, sinT);
    gemm_bt8<1><<<dim3(256), 512, 0, stream>>>(xb, Wall, qkv, 4096, 3072, 2048);
    scatter_vt_kernel<<<3072, 256, 0, stream>>>(qkv, cosT, sinT, Qs, Ks, Vts);
    attn_kernel<<<dim3(512), 256, 0, stream>>>(Qs, Ks, Vts, Yb);
    gemm_bt<0><<<dim3(32 * 16), 256, 0, stream>>>(Yb, wob, out, 4096, 2048, 2048);
}